// Round 6
// baseline (327.985 us; speedup 1.0000x reference)
//
#include <hip/hip_runtime.h>
#include <hip/hip_bf16.h>

typedef unsigned short u16;
typedef __attribute__((ext_vector_type(8))) short bf16x8;
typedef __attribute__((ext_vector_type(4))) float f32x4;

#define BTOK 4096
#define DDIM 1024
#define NEXP 8
#define HDIM 4096
#define ODIM 1024
#define MAXTILES 40
#define MAXROWS (MAXTILES * 128)  // 5120

__device__ __forceinline__ u16 f2bf(float f) {
  unsigned u = __float_as_uint(f);
  return (u16)((u + 0x7FFFu + ((u >> 16) & 1u)) >> 16);  // RNE
}
__device__ __forceinline__ u16 cvt_bf(float f) {  // HW cvt, RNE
  __hip_bfloat16 h = __float2bfloat16(f);
  u16 r;
  __builtin_memcpy(&r, &h, 2);
  return r;
}

__device__ __forceinline__ void gload16(const void* g, void* l) {
  __builtin_amdgcn_global_load_lds(
      (const __attribute__((address_space(1))) void*)g,
      (__attribute__((address_space(3))) void*)l, 16, 0, 0);
}

// ---------------- init: clear control block + rowmap ----------------
__global__ __launch_bounds__(256) void init_kernel(int* __restrict__ ctrl,
                                                   int* __restrict__ rowmap) {
  int i = blockIdx.x * 256 + threadIdx.x;
  if (i < 1024)
    ctrl[i] = 0;
  else
    rowmap[i - 1024] = -1;  // 5120 entries
}

// ---------------- gating: one wave per token, fp64 accumulate ----------------
__global__ __launch_bounds__(256) void gate_kernel(
    const float* __restrict__ x, const float* __restrict__ Wg,
    const float* __restrict__ bg, int* __restrict__ assign,
    int* __restrict__ counts) {
  int wave = threadIdx.x >> 6;
  int lane = threadIdx.x & 63;
  int b = blockIdx.x * 4 + wave;
  const float* xr = x + (size_t)b * DDIM;
  double acc[NEXP];
#pragma unroll
  for (int e = 0; e < NEXP; ++e) acc[e] = 0.0;
  for (int d = lane; d < DDIM; d += 64) {
    float xv = xr[d];
    const float4* wrow = (const float4*)(Wg + d * NEXP);
    float4 w0 = wrow[0], w1 = wrow[1];
    acc[0] += (double)xv * (double)w0.x;
    acc[1] += (double)xv * (double)w0.y;
    acc[2] += (double)xv * (double)w0.z;
    acc[3] += (double)xv * (double)w0.w;
    acc[4] += (double)xv * (double)w1.x;
    acc[5] += (double)xv * (double)w1.y;
    acc[6] += (double)xv * (double)w1.z;
    acc[7] += (double)xv * (double)w1.w;
  }
#pragma unroll
  for (int e = 0; e < NEXP; ++e) {
    double v = acc[e];
#pragma unroll
    for (int off = 32; off > 0; off >>= 1) v += __shfl_xor(v, off);
    acc[e] = v;
  }
  if (lane == 0) {
    int best = 0;
    double bv = acc[0] + (double)bg[0];
#pragma unroll
    for (int e = 1; e < NEXP; ++e) {
      double v = acc[e] + (double)bg[e];
      if (v > bv) { bv = v; best = e; }  // first max wins (matches jnp.argmax)
    }
    assign[b] = best;
    atomicAdd(&counts[best], 1);
  }
}

// ---------------- setup: offsets, tile table, balance loss ----------------
__global__ void setup_kernel(const int* __restrict__ counts,
                             const float* __restrict__ wbal,
                             int* __restrict__ offp, int* __restrict__ tile_e,
                             int* __restrict__ tile_m, int* __restrict__ meta,
                             float* __restrict__ loss_out) {
  if (threadIdx.x != 0 || blockIdx.x != 0) return;
  int off = 0, nt = 0;
  for (int e = 0; e < NEXP; ++e) {
    offp[e] = off;
    int pc = (counts[e] + 127) & ~127;  // pad to 128
    for (int t = 0; t < (pc >> 7); ++t) {
      tile_e[nt] = e;
      tile_m[nt] = off + t * 128;
      ++nt;
    }
    off += pc;
  }
  offp[NEXP] = off;
  meta[0] = nt;
  float mean = (float)BTOK / (float)NEXP;
  float s = 0.f;
  for (int e = 0; e < NEXP; ++e) {
    float d = (float)counts[e] - mean;
    s += d * d;
  }
  loss_out[0] = s / (float)NEXP * wbal[0];
}

// ---------------- gather: token -> per-expert bucket, fp32 -> bf16 ------------
__global__ __launch_bounds__(256) void gather_kernel(
    const float* __restrict__ x, const int* __restrict__ assign,
    const int* __restrict__ offp, int* __restrict__ fill,
    int* __restrict__ rowmap, u16* __restrict__ xg) {
  int b = blockIdx.x;
  __shared__ int srow;
  if (threadIdx.x == 0) {
    int e = assign[b];
    int pos = atomicAdd(&fill[e], 1);
    int row = offp[e] + pos;
    rowmap[row] = b;
    srow = row;
  }
  __syncthreads();
  int row = srow;
  float4 v = *(const float4*)(x + (size_t)b * DDIM + threadIdx.x * 4);
  ushort4 o;
  o.x = f2bf(v.x);
  o.y = f2bf(v.y);
  o.z = f2bf(v.z);
  o.w = f2bf(v.w);
  *(ushort4*)(xg + (size_t)row * DDIM + threadIdx.x * 4) = o;
}

// ---------------- grouped GEMM, fused B transpose, counted-waitcnt pipeline ---
// Tile 128x128, BK=32, 4 waves, mfma 16x16x32_bf16, acc 4x4.
// A (bf16 K-contig): global_load_lds into 3-buffer rotation, staged 2 ahead.
// B (fp32 [K][LDN] N-contig): 16 lane-coalesced strided loads into ping-pong
//   reg files loaded 2 ahead; cvt+2x ds_write_b128 (swizzled) one ahead.
// Raw s_barrier + own lgkmcnt(0): in-flight loads (next A + next-next B)
// survive the barrier (T4). Per-wave vmcnt ledger: issue order stageA(t+2)
// then loadB(t+2); the compiler's auto-vmcnt before writeB's cvt (fb(t+1))
// also retires stageA(t+1) - exactly what compute(t+1) needs post-barrier.
// LDS swizzle unit(r,kq) = r*4 + (kq ^ ((r>>1)&3)): b128 reads/writes 2-way.
// MODE 0: Hout = relu(acc + bias) bf16;  MODE 1: P[z] = acc (fp32 partials)
template <int MODE, int LDA, int LDN>
__global__ __launch_bounds__(256, 3) void moe_gemm(
    const u16* __restrict__ A, const float* __restrict__ W, size_t eStride,
    const float* __restrict__ bias, const int* __restrict__ tile_e,
    const int* __restrict__ tile_m, const int* __restrict__ meta,
    u16* __restrict__ Hout, float* __restrict__ P, size_t pStride, int nkt) {
  // bijective XCD swizzle (nwg % 8 == 0 for all our grids)
  const int nx = gridDim.x;
  const int nwg = nx * gridDim.y;
  const int orig = blockIdx.y * nx + blockIdx.x;
  const int q = nwg >> 3;
  const int wg = (orig & 7) * q + (orig >> 3);
  const int bx = wg % nx, by = wg / nx;
  if (bx >= meta[0]) return;
  const int e = tile_e[bx];
  const int m0 = tile_m[bx];
  const int n0 = by * 128;
  const int kOff = blockIdx.z * nkt * 32;

  __shared__ __align__(16) u16 Alds[3 * 4096];  // 3 x 8 KB
  __shared__ __align__(16) u16 Blds[2 * 4096];  // 2 x 8 KB

  const int tid = threadIdx.x;
  const int lane = tid & 63;
  const int wave = tid >> 6;
  const int wr = wave >> 1, wc = wave & 1;
  const int fr = lane & 15;
  const int kqr = lane >> 4;

  // ---- A staging (global_load_lds, inverse-swizzled source) ----
  const int r0 = tid >> 2, k0 = (tid & 3) ^ ((r0 >> 1) & 3);
  const int r1 = (tid + 256) >> 2, k1 = ((tid + 256) & 3) ^ ((r1 >> 1) & 3);
  const u16* aS0 = A + (size_t)(m0 + r0) * LDA + kOff + k0 * 8;
  const u16* aS1 = A + (size_t)(m0 + r1) * LDA + kOff + k1 * 8;
  const int dst0 = (tid & ~63) * 8;  // u16 units, lane-linear per wave
  const int dst1 = dst0 + 2048;

  // ---- B staging (fused transpose+convert) ----
  const int bc = tid & 127;   // output column 0..127
  const int bq0 = tid >> 7;   // k-octs {bq0, bq0+2}
  const float* bRow = W + (size_t)e * eStride + (size_t)kOff * LDN + n0 + bc;
  const int bu0 = (bc * 4 + (bq0 ^ ((bc >> 1) & 3))) * 8;        // u16 units
  const int bu1 = (bc * 4 + ((bq0 + 2) ^ ((bc >> 1) & 3))) * 8;  // u16 units

  // fragment offsets (u16 units, swizzled)
  int aOff[4], bOff[4];
#pragma unroll
  for (int i = 0; i < 4; ++i) {
    int r = wr * 64 + i * 16 + fr;
    aOff[i] = (r * 4 + (kqr ^ ((r >> 1) & 3))) * 8;
    int c = wc * 64 + i * 16 + fr;
    bOff[i] = (c * 4 + (kqr ^ ((c >> 1) & 3))) * 8;
  }

  f32x4 acc[4][4];
#pragma unroll
  for (int i = 0; i < 4; ++i)
#pragma unroll
    for (int j = 0; j < 4; ++j)
#pragma unroll
      for (int r = 0; r < 4; ++r) acc[i][j][r] = 0.f;

  float fb0[16], fb1[16];  // named ping-pong (no runtime-indexed reg arrays)

  auto stageA = [&](int buf, int kt) {
    const int ko = kt * 32;
    u16* base = Alds + buf * 4096;
    gload16(aS0 + ko, base + dst0);
    gload16(aS1 + ko, base + dst1);
  };
  auto loadB = [&](float (&f)[16], int kt) {
    const float* p = bRow + (size_t)kt * 32 * LDN;
#pragma unroll
    for (int i = 0; i < 8; ++i) f[i] = p[(size_t)(bq0 * 8 + i) * LDN];
#pragma unroll
    for (int i = 0; i < 8; ++i) f[8 + i] = p[(size_t)((bq0 + 2) * 8 + i) * LDN];
  };
  auto writeB = [&](const float (&f)[16], int buf) {
    u16* ldsB = Blds + buf * 4096;
    alignas(16) u16 tA[8], tB[8];
#pragma unroll
    for (int i = 0; i < 8; ++i) tA[i] = cvt_bf(f[i]);
#pragma unroll
    for (int i = 0; i < 8; ++i) tB[i] = cvt_bf(f[8 + i]);
    *(bf16x8*)&ldsB[bu0] = *(const bf16x8*)tA;
    *(bf16x8*)&ldsB[bu1] = *(const bf16x8*)tB;
  };
  auto compute = [&](int abuf, int bbuf) {
    const u16* aB = Alds + abuf * 4096;
    const u16* bB = Blds + bbuf * 4096;
    bf16x8 af[4], bfr[4];
#pragma unroll
    for (int i = 0; i < 4; ++i) {
      af[i] = *(const bf16x8*)(aB + aOff[i]);
      bfr[i] = *(const bf16x8*)(bB + bOff[i]);
    }
#pragma unroll
    for (int i = 0; i < 4; ++i)
#pragma unroll
      for (int j = 0; j < 4; ++j)
        acc[i][j] = __builtin_amdgcn_mfma_f32_16x16x32_bf16(af[i], bfr[j],
                                                            acc[i][j], 0, 0, 0);
  };

#define BAR()                                              \
  asm volatile("s_waitcnt lgkmcnt(0)" ::: "memory");       \
  __builtin_amdgcn_sched_barrier(0);                       \
  __builtin_amdgcn_s_barrier();                            \
  __builtin_amdgcn_sched_barrier(0);

  // STEP(t): stage t+2, load B(t+2) into FN, compute t, write B(t+1) from FC
#define STEP(T, FC, FN)                                    \
  {                                                        \
    if ((T) + 2 < nkt) {                                   \
      stageA(sa, (T) + 2);                                 \
      sa = (sa == 2) ? 0 : sa + 1;                         \
      loadB(FN, (T) + 2);                                  \
    }                                                      \
    compute(ca, (T) & 1);                                  \
    ca = (ca == 2) ? 0 : ca + 1;                           \
    writeB(FC, ((T) + 1) & 1);                             \
    BAR();                                                 \
  }

  // prologue: A(0),A(1) staged; B(0) written; B(1) in flight in fb1
  stageA(0, 0);
  stageA(1, 1);
  loadB(fb0, 0);
  writeB(fb0, 0);  // auto-vmcnt drains stageA(0)/(1) + fb0
  loadB(fb0, 1);
  BAR();

  int ca = 0, sa = 2;
  STEP(0, fb0, fb1);  // fb0 holds B(1); loads B(2) into fb1
#pragma unroll 1
  for (int t = 1; t + 1 < nkt; t += 2) {
    STEP(t, fb1, fb0);      // odd t: consume fb1, load into fb0
    STEP(t + 1, fb0, fb1);  // even t: consume fb0, load into fb1
  }
  compute(ca, (nkt - 1) & 1);
#undef STEP
#undef BAR

  // epilogue: C/D layout col = lane&15, row = (lane>>4)*4 + reg
  if constexpr (MODE == 0) {
#pragma unroll
    for (int i = 0; i < 4; ++i) {
      int rbase = m0 + wr * 64 + i * 16 + (lane >> 4) * 4;
#pragma unroll
      for (int j = 0; j < 4; ++j) {
        int col = n0 + wc * 64 + j * 16 + fr;
        float bv = bias[e * LDN + col];
#pragma unroll
        for (int r = 0; r < 4; ++r) {
          float v = acc[i][j][r] + bv;
          v = v > 0.f ? v : 0.f;
          Hout[(size_t)(rbase + r) * LDN + col] = f2bf(v);
        }
      }
    }
  } else {
    float* Pp = P + blockIdx.z * pStride;
#pragma unroll
    for (int i = 0; i < 4; ++i) {
      int rbase = m0 + wr * 64 + i * 16 + (lane >> 4) * 4;
#pragma unroll
      for (int j = 0; j < 4; ++j) {
        int col = n0 + wc * 64 + j * 16 + fr;
#pragma unroll
        for (int r = 0; r < 4; ++r)
          Pp[(size_t)(rbase + r) * ODIM + col] = acc[i][j][r];
      }
    }
  }
}

// ---------------- reduce: out[tok] = P0 + P1 + b2 ----------------
__global__ __launch_bounds__(256) void reduce_kernel(
    const float* __restrict__ P, size_t pStride, const int* __restrict__ rowmap,
    const int* __restrict__ tile_e, const int* __restrict__ tile_m,
    const int* __restrict__ meta, const float* __restrict__ b2,
    float* __restrict__ out) {
  if ((int)blockIdx.x >= meta[0]) return;
  const int e = tile_e[blockIdx.x];
  const int m0 = tile_m[blockIdx.x];
  const int c0 = blockIdx.y * 128;
#pragma unroll 1
  for (int it = 0; it < 16; ++it) {
    int idx = it * 256 + threadIdx.x;  // 4096 float4 per block
    int r = idx >> 5, cq = idx & 31;
    int row = m0 + r;
    int tok = rowmap[row];
    if (tok < 0) continue;
    int c = c0 + cq * 4;
    float4 a = *(const float4*)(P + (size_t)row * ODIM + c);
    float4 b = *(const float4*)(P + pStride + (size_t)row * ODIM + c);
    float4 bb = *(const float4*)(b2 + (size_t)e * ODIM + c);
    float4 o;
    o.x = a.x + b.x + bb.x;
    o.y = a.y + b.y + bb.y;
    o.z = a.z + b.z + bb.z;
    o.w = a.w + b.w + bb.w;
    *(float4*)(out + (size_t)tok * ODIM + c) = o;
  }
}

extern "C" void kernel_launch(void* const* d_in, const int* in_sizes, int n_in,
                              void* d_out, int out_size, void* d_ws,
                              size_t ws_size, hipStream_t stream) {
  const float* x = (const float*)d_in[0];
  const float* Wg = (const float*)d_in[1];
  const float* bg = (const float*)d_in[2];
  const float* W1 = (const float*)d_in[3];
  const float* b1 = (const float*)d_in[4];
  const float* W2 = (const float*)d_in[5];
  const float* b2 = (const float*)d_in[6];
  const float* wbal = (const float*)d_in[7];
  float* out = (float*)d_out;

  char* ws = (char*)d_ws;
  int* counts = (int*)(ws + 0);
  int* fill = (int*)(ws + 64);
  int* offp = (int*)(ws + 128);
  int* meta = (int*)(ws + 192);
  int* tile_e = (int*)(ws + 256);
  int* tile_m = (int*)(ws + 512);
  int* assign = (int*)(ws + 4096);
  int* rowmap = (int*)(ws + 20480);
  u16* xg = (u16*)(ws + 65536);                    // 5120 x 1024 bf16 (10.5 MB)
  u16* h = (u16*)(ws + 10551296);                  // 5120 x 4096 bf16 (41.9 MB)
  float* P = (float*)(ws + 52494336);              // 2 x 5120 x 1024 f32 (41.9 MB)
  const size_t pStride = (size_t)MAXROWS * ODIM;   // floats per partial

  init_kernel<<<24, 256, 0, stream>>>((int*)ws, rowmap);
  gate_kernel<<<BTOK / 4, 256, 0, stream>>>(x, Wg, bg, assign, counts);
  setup_kernel<<<1, 64, 0, stream>>>(counts, wbal, offp, tile_e, tile_m, meta,
                                     out + (size_t)BTOK * ODIM);
  gather_kernel<<<BTOK, 256, 0, stream>>>(x, assign, offp, fill, rowmap, xg);

  // GEMM1: h = relu(xg @ W1 + b1)   A: [5120][1024] bf16, B: W1 fp32 [1024][4096]
  moe_gemm<0, DDIM, HDIM><<<dim3(MAXTILES, HDIM / 128, 1), 256, 0, stream>>>(
      xg, W1, (size_t)DDIM * HDIM, b1, tile_e, tile_m, meta, h, nullptr, 0,
      DDIM / 32);
  // GEMM2: P[z] = h @ W2 (K split z=2)   A: [5120][4096] bf16, B: W2 fp32 [4096][1024]
  moe_gemm<1, HDIM, ODIM><<<dim3(MAXTILES, ODIM / 128, 2), 256, 0, stream>>>(
      h, W2, (size_t)HDIM * ODIM, nullptr, tile_e, tile_m, meta, nullptr, P,
      pStride, HDIM / 64);

  reduce_kernel<<<dim3(MAXTILES, ODIM / 128), 256, 0, stream>>>(
      P, pStride, rowmap, tile_e, tile_m, meta, b2, out);
}